// Round 11
// baseline (267.387 us; speedup 1.0000x reference)
//
#include <hip/hip_runtime.h>

// Chamfer forward: dist0[i] = min_j ||pc0[i]-pc1[j]||^2 ; out = mean(dist0[dist0<=2])
// N = M = 65536 i.i.d. N(0,1)^3 points, fp32.
// Spatial grid (counting sort), 32^3 cells, h=0.25 over [-4,4]^3 (clamp = contraction,
// ring bound stays valid). Queries sorted too (output is permutation-invariant).
// ROUND 11: query was still latency-bound (12% VALUBusy, 10.8% occ): the 9 rows'
// starts[] loads were serial (~400 cyc each). Now: (1) preload all 9 row ranges
// up-front (18 independent loads, one wait); (2) 8 lanes/query -> 2048 blocks =
// 8 waves/SIMD; (3) scan split across 2 blocks; (4) finalize fused into query via
// done-counter (device-scope atomic reads dodge cross-XCD L2 staleness).

constexpr int   NPTS  = 65536;
constexpr int   GRID  = 32;
constexpr int   NC    = GRID * GRID * GRID;   // 32768 cells
constexpr float H     = 0.25f;
constexpr float ORG   = -4.0f;
constexpr float INVH  = 4.0f;
constexpr int   BLOCK = 256;
constexpr int   QBLOCKS = 8 * NPTS / BLOCK;   // 2048 query blocks

__device__ __forceinline__ int cellOf(float x) {
  int c = (int)floorf((x - ORG) * INVH);
  return min(max(c, 0), GRID - 1);
}

__global__ __launch_bounds__(BLOCK) void count_kernel(
    const float* __restrict__ pc0, const float* __restrict__ pc1,
    unsigned* __restrict__ counts0, unsigned* __restrict__ counts1) {
  const int gid = blockIdx.x * BLOCK + threadIdx.x;
  const float* p; unsigned* cnt; int i;
  if (gid < NPTS) { p = pc1; cnt = counts1; i = gid; }
  else            { p = pc0; cnt = counts0; i = gid - NPTS; }
  const float x = p[3 * i], y = p[3 * i + 1], z = p[3 * i + 2];
  const int cid = (cellOf(z) * GRID + cellOf(y)) * GRID + cellOf(x);
  atomicAdd(&cnt[cid], 1u);
}

// Exclusive scan of NC elements, shfl-based (1024 threads x 32 cells each).
__device__ void scan_one(const unsigned* __restrict__ counts,
                         unsigned* __restrict__ starts,
                         unsigned* __restrict__ cursor,
                         unsigned* waveTot /* [16] */) {
  const int tid = threadIdx.x;
  constexpr int PER = NC / 1024;   // 32
  const int base = tid * PER;
  unsigned loc[PER];
  unsigned run = 0;
  for (int j = 0; j < PER; ++j) { loc[j] = counts[base + j]; run += loc[j]; }
  unsigned inc = run;
  for (int off = 1; off < 64; off <<= 1) {
    const unsigned v = __shfl_up(inc, off, 64);
    if ((tid & 63) >= off) inc += v;
  }
  if ((tid & 63) == 63) waveTot[tid >> 6] = inc;
  __syncthreads();
  if (tid < 16) {
    unsigned w = waveTot[tid];
    for (int off = 1; off < 16; off <<= 1) {
      const unsigned v = __shfl_up(w, off, 16);
      if (tid >= off) w += v;
    }
    waveTot[tid] = w;
  }
  __syncthreads();
  const unsigned waveOff = (tid >> 6) == 0 ? 0u : waveTot[(tid >> 6) - 1];
  unsigned r = waveOff + inc - run;
  for (int j = 0; j < PER; ++j) { starts[base + j] = r; cursor[base + j] = r; r += loc[j]; }
  if (tid == 1023) starts[NC] = r;
}

__global__ __launch_bounds__(1024) void scan_kernel(
    const unsigned* __restrict__ counts0, unsigned* __restrict__ starts0,
    unsigned* __restrict__ cursor0,
    const unsigned* __restrict__ counts1, unsigned* __restrict__ starts1,
    unsigned* __restrict__ cursor1) {
  __shared__ unsigned waveTot[16];
  if (blockIdx.x == 0) scan_one(counts1, starts1, cursor1, waveTot);
  else                 scan_one(counts0, starts0, cursor0, waveTot);
}

__global__ __launch_bounds__(BLOCK) void scatter_kernel(
    const float* __restrict__ pc0, const float* __restrict__ pc1,
    unsigned* __restrict__ cursor0, unsigned* __restrict__ cursor1,
    float4* __restrict__ q, float4* __restrict__ s) {
  const int gid = blockIdx.x * BLOCK + threadIdx.x;
  const float* p; unsigned* cur; float4* dst; int i;
  if (gid < NPTS) { p = pc1; cur = cursor1; dst = s; i = gid; }
  else            { p = pc0; cur = cursor0; dst = q; i = gid - NPTS; }
  const float x = p[3 * i], y = p[3 * i + 1], z = p[3 * i + 2];
  const int cid = (cellOf(z) * GRID + cellOf(y)) * GRID + cellOf(x);
  const unsigned pos = atomicAdd(&cur[cid], 1u);
  dst[pos] = make_float4(x, y, z, 0.f);
}

// 8 lanes cooperate per query; lanes stride candidate rows by 8.
__global__ __launch_bounds__(BLOCK) void query_kernel(
    const float4* __restrict__ q,
    const unsigned* __restrict__ starts,
    const float4* __restrict__ s,
    float* __restrict__ accum /* [0]=sum, [1]=count */,
    unsigned* __restrict__ done, float* __restrict__ out) {
  const int gtid = blockIdx.x * BLOCK + threadIdx.x;
  const int i   = gtid >> 3;        // query index
  const int sub = gtid & 7;         // sub-lane within the 8-lane group
  const float4 p = q[i];
  const int cx = cellOf(p.x), cy = cellOf(p.y), cz = cellOf(p.z);
  float best = 3.4e38f;

  // preload the 9 row ranges of the 3x3x3 neighborhood (independent loads)
  unsigned rs[9], re[9];
  {
    const int x0 = max(cx - 1, 0), x1 = min(cx + 1, GRID - 1);
#pragma unroll
    for (int rr = 0; rr < 9; ++rr) {
      const int zz = cz + rr / 3 - 1, yy = cy + rr % 3 - 1;
      const bool ok = (zz >= 0) & (zz < GRID) & (yy >= 0) & (yy < GRID);
      const int rb = ok ? (zz * GRID + yy) * GRID : 0;
      rs[rr] = ok ? starts[rb + x0] : 0u;
      re[rr] = ok ? starts[rb + x1 + 1] : 0u;
    }
  }
#pragma unroll
  for (int rr = 0; rr < 9; ++rr) {
    for (unsigned j = rs[rr] + sub; j < re[rr]; j += 8) {
      const float4 c = s[j];
      const float ddx = p.x - c.x;
      const float ddy = p.y - c.y;
      const float ddz = p.z - c.z;
      best = fminf(best, fmaf(ddx, ddx, fmaf(ddy, ddy, ddz * ddz)));
    }
  }

  // combine across the 8 sub-lanes (group-uniform ring decisions)
  best = fminf(best, __shfl_xor(best, 1, 64));
  best = fminf(best, __shfl_xor(best, 2, 64));
  best = fminf(best, __shfl_xor(best, 4, 64));

  // rare ring expansion: after rings 0..r-1, unsearched points >= (r-1)*h away
  auto scanRow = [&](int zz, int yy, int x0, int x1) {
    if (zz < 0 || zz >= GRID || yy < 0 || yy >= GRID) return;
    x0 = max(x0, 0); x1 = min(x1, GRID - 1);
    if (x0 > x1) return;
    const int rb = (zz * GRID + yy) * GRID;
    unsigned j = starts[rb + x0] + sub;
    const unsigned e = starts[rb + x1 + 1];
    for (; j < e; j += 8) {
      const float4 c = s[j];
      const float ddx = p.x - c.x;
      const float ddy = p.y - c.y;
      const float ddz = p.z - c.z;
      best = fminf(best, fmaf(ddx, ddx, fmaf(ddy, ddy, ddz * ddz)));
    }
  };
  for (int r = 2; r <= GRID; ++r) {
    const float cov = H * (float)(r - 1);
    if (best <= cov * cov) break;
    for (int dz = -r; dz <= r; ++dz) {
      const int zz = cz + dz;
      if (zz < 0 || zz >= GRID) continue;
      if (dz == -r || dz == r) {
        for (int dy = -r; dy <= r; ++dy)
          scanRow(zz, cy + dy, cx - r, cx + r);
      } else {
        scanRow(zz, cy - r, cx - r, cx + r);
        scanRow(zz, cy + r, cx - r, cx + r);
        for (int dy = -r + 1; dy <= r - 1; ++dy) {
          scanRow(zz, cy + dy, cx - r, cx - r);
          scanRow(zz, cy + dy, cx + r, cx + r);
        }
      }
    }
    best = fminf(best, __shfl_xor(best, 1, 64));
    best = fminf(best, __shfl_xor(best, 2, 64));
    best = fminf(best, __shfl_xor(best, 4, 64));
  }

  // masked mean contribution: only sub-lane 0 of each group contributes
  float v = (sub == 0 && best <= 2.0f) ? best : 0.0f;
  float c = (sub == 0 && best <= 2.0f) ? 1.0f : 0.0f;
  for (int off = 32; off > 0; off >>= 1) {
    v += __shfl_down(v, off, 64);
    c += __shfl_down(c, off, 64);
  }
  __shared__ float wsum[BLOCK / 64], wcnt[BLOCK / 64];
  const int wid = threadIdx.x >> 6;
  if ((threadIdx.x & 63) == 0) { wsum[wid] = v; wcnt[wid] = c; }
  __syncthreads();
  if (threadIdx.x == 0) {
    float sS = 0.f, cS = 0.f;
    for (int w = 0; w < BLOCK / 64; ++w) { sS += wsum[w]; cS += wcnt[w]; }
    atomicAdd(&accum[0], sS);
    atomicAdd(&accum[1], cS);
    __threadfence();                       // order accum adds before done tick
    const unsigned prev = atomicAdd(done, 1u);
    if (prev == (unsigned)(QBLOCKS - 1)) { // last block finalizes
      const float fs = atomicAdd(&accum[0], 0.0f);  // device-scope coherent read
      const float fc = atomicAdd(&accum[1], 0.0f);
      out[0] = fs / fc;
    }
  }
}

extern "C" void kernel_launch(void* const* d_in, const int* in_sizes, int n_in,
                              void* d_out, int out_size, void* d_ws, size_t ws_size,
                              hipStream_t stream) {
  const float* pc0 = (const float*)d_in[0];
  const float* pc1 = (const float*)d_in[1];
  float* out = (float*)d_out;

  // slab carve-up; counts1|counts0|accum-block contiguous -> single memset
  char* w = (char*)d_ws;
  auto nxt = [&](size_t bytes) {
    char* p = w; w += (bytes + 255) & ~(size_t)255; return p;
  };
  unsigned* counts1 = (unsigned*)nxt((size_t)NC * 4);
  unsigned* counts0 = (unsigned*)nxt((size_t)NC * 4);
  float*    accum   = (float*)nxt(256);   // [0]=sum,[1]=count,[2]=done
  unsigned* done    = (unsigned*)(accum + 2);
  unsigned* starts1 = (unsigned*)nxt((size_t)(NC + 1) * 4);
  unsigned* cursor1 = (unsigned*)nxt((size_t)NC * 4);
  unsigned* starts0 = (unsigned*)nxt((size_t)(NC + 1) * 4);
  unsigned* cursor0 = (unsigned*)nxt((size_t)NC * 4);
  float4* s = (float4*)nxt((size_t)NPTS * 16);
  float4* q = (float4*)nxt((size_t)NPTS * 16);

  hipMemsetAsync(counts1, 0, (size_t)2 * NC * 4 + 256, stream);

  count_kernel<<<2 * NPTS / BLOCK, BLOCK, 0, stream>>>(pc0, pc1, counts0, counts1);
  scan_kernel<<<2, 1024, 0, stream>>>(counts0, starts0, cursor0,
                                      counts1, starts1, cursor1);
  scatter_kernel<<<2 * NPTS / BLOCK, BLOCK, 0, stream>>>(
      pc0, pc1, cursor0, cursor1, q, s);
  query_kernel<<<QBLOCKS, BLOCK, 0, stream>>>(q, starts1, s, accum, done, out);
}